// Round 7
// baseline (177.579 us; speedup 1.0000x reference)
//
#include <hip/hip_runtime.h>

// 3x3 median blur + residual, zero padding, x:(8,3,1024,1024) f32.
// Round-5 copy-clone microstructure (resubmit; R6 bench was
// GPUAcquisitionTimeout, never ran). R0-R3 proved four different schedules
// (reg-burst / reg-ring / LDS-DMA counted-vmcnt / asm-pinned deep MLP) all
// run at EXACTLY 62us, 2.5 TB/s, VALUBusy 23%, Occupancy 40% -> the
// schedule is not the limiter. The known-good 6.3 TB/s pattern (m13 float4
// copy) differs in microstructure: 32 shallow waves/CU, ~2 vmem ops/wave,
// dispatch-order contiguous sweep. This kernel clones that: one output ROW
// per 256-thread block, 3 row-loads + 1 store per thread, halos by
// intra-wave shfl + masked wave-boundary dwords (no LDS, no barrier, waves
// independent), grid 1024x24 in row order -> ~2048-row sliding window;
// neighbor blocks share 2 of 3 input rows via L2/L3 inside the window.
// __launch_bounds__(256,8): VGPR<=64 -> 8 blocks/CU, max TLP.

typedef float v4f __attribute__((ext_vector_type(4)));

#define S2(a,b) { float _t=fminf(a,b); (b)=fmaxf(a,b); (a)=_t; }
__device__ __forceinline__ float med3f(float a, float b, float c) {
    return fmaxf(fminf(a, b), fminf(fmaxf(a, b), c));
}

constexpr int W = 1024, H = 1024;

__global__ __launch_bounds__(256, 8) void median_blur_kernel(
    const float* __restrict__ xin, float* __restrict__ out)
{
    const int tx   = threadIdx.x;
    const int lane = tx & 63;
    const int x0   = tx << 2;                    // 4 px per thread, full row
    const int y    = (int)blockIdx.x;            // one output row per block
    const size_t plane = (size_t)blockIdx.y * (size_t)(H * W);
    const float* base  = xin + plane;

    const int yt = y > 0     ? y - 1 : 0;        // clamped addr; zeroed below
    const int yb = y < H - 1 ? y + 1 : H - 1;
    const float* rpt = base + ((size_t)yt << 10);
    const float* rpm = base + ((size_t)y  << 10);
    const float* rpb = base + ((size_t)yb << 10);

    // 3 coalesced dwordx4 loads per thread (the whole read side)
    v4f ct = *reinterpret_cast<const v4f*>(rpt + x0);
    v4f cm = *reinterpret_cast<const v4f*>(rpm + x0);
    v4f cb = *reinterpret_cast<const v4f*>(rpb + x0);

    // horizontal halos: intra-wave shfl; wave-boundary lanes load the dword
    float hlt = __shfl_up(ct.w, 1);
    float hlm = __shfl_up(cm.w, 1);
    float hlb = __shfl_up(cb.w, 1);
    float hrt = __shfl_down(ct.x, 1);
    float hrm = __shfl_down(cm.x, 1);
    float hrb = __shfl_down(cb.x, 1);
    if (lane == 0) {
        if (tx == 0) { hlt = 0.0f; hlm = 0.0f; hlb = 0.0f; }   // image left edge
        else         { hlt = rpt[x0 - 1]; hlm = rpm[x0 - 1]; hlb = rpb[x0 - 1]; }
    }
    if (lane == 63) {
        if (tx == 255) { hrt = 0.0f; hrm = 0.0f; hrb = 0.0f; } // image right edge
        else           { hrt = rpt[x0 + 4]; hrm = rpm[x0 + 4]; hrb = rpb[x0 + 4]; }
    }

    float t[6] = { hlt, ct.x, ct.y, ct.z, ct.w, hrt };
    float m[6] = { hlm, cm.x, cm.y, cm.z, cm.w, hrm };
    float b[6] = { hlb, cb.x, cb.y, cb.z, cb.w, hrb };
    if (y == 0) {                                 // input row -1 is zero padding
#pragma unroll
        for (int j = 0; j < 6; ++j) t[j] = 0.0f;
    }
    if (y == H - 1) {                             // input row H is zero padding
#pragma unroll
        for (int j = 0; j < 6; ++j) b[j] = 0.0f;
    }

    // vertical sort3 per column, then med3-of-candidates per output px
    float lo[6], mi[6], hi[6];
#pragma unroll
    for (int j = 0; j < 6; ++j) {
        float a = t[j], c0 = m[j], d = b[j];
        S2(a, c0); S2(c0, d); S2(a, c0);
        lo[j] = a; mi[j] = c0; hi[j] = d;
    }
    v4f o;
#pragma unroll
    for (int j = 0; j < 4; ++j) {
        const float mxlo = fmaxf(lo[j], fmaxf(lo[j + 1], lo[j + 2]));
        const float mnhi = fminf(hi[j], fminf(hi[j + 1], hi[j + 2]));
        const float mdmi = med3f(mi[j], mi[j + 1], mi[j + 2]);
        const float med  = med3f(mxlo, mdmi, mnhi);
        const float xc   = m[j + 1];
        o[j] = xc + 0.2f * (med - xc);
    }
    *reinterpret_cast<v4f*>(out + plane + ((size_t)y << 10) + x0) = o;
}

extern "C" void kernel_launch(void* const* d_in, const int* in_sizes, int n_in,
                              void* d_out, int out_size, void* d_ws, size_t ws_size,
                              hipStream_t stream) {
    const float* x = (const float*)d_in[0];
    float* out = (float*)d_out;
    const int planes = in_sizes[0] / (H * W);     // 24
    dim3 block(256);
    dim3 grid(H, planes);                         // 1024 x 24 = 24576 blocks, row order
    median_blur_kernel<<<grid, block, 0, stream>>>(x, out);
}